// Round 8
// baseline (120.099 us; speedup 1.0000x reference)
//
#include <hip/hip_runtime.h>

#define NN 4096
#define FIN 256
#define CC 256
#define NH 8
#define NW32 (NN / 32)  // u32 words per adj row

typedef __attribute__((ext_vector_type(8))) short short8;
typedef __attribute__((ext_vector_type(4))) float f32x4;
typedef __attribute__((ext_vector_type(4))) unsigned int u32x4;

__device__ __forceinline__ unsigned cvtpk_bf16(float lo, float hi) {
  unsigned r;
  asm("v_cvt_pk_bf16_f32 %0, %1, %2" : "=v"(r) : "v"(lo), "v"(hi));
  return r;
}

__device__ __forceinline__ unsigned short bf16rn(float x) {
  unsigned int u = __builtin_bit_cast(unsigned int, x);
  u += 0x7fffu + ((u >> 16) & 1u);
  return (unsigned short)(u >> 16);
}

// ---------------- K1: adj bitpack + g = h@W with fused epilogue ------------
// adjb[i][w] bit e = (adj[i][w*32+e] != 0).
// gT (bf16, [c=h*32+f][n]); spack[h][n] = (s_src, e^s, e^.2s, 0);
// dtrip blocked [h][n>>3][3][8] = (-s_dst, e^sd, e^{0.2 sd}).
#define GROWS 8
__global__ __launch_bounds__(256) void k_gemm(
    const float* __restrict__ h, const float* __restrict__ W,
    const float* __restrict__ a, const int* __restrict__ adj,
    unsigned int* __restrict__ adjb, unsigned short* __restrict__ gT,
    float4* __restrict__ spack, float* __restrict__ dtrip) {
  __shared__ float hs[GROWS][FIN];
  const int t = threadIdx.x;

  // --- bitpack 8 adj rows (this block's slice); overlaps other blocks' GEMM
  {
    const int rbase = blockIdx.x * 8;
#pragma unroll
    for (int k = 0; k < 4; ++k) {
      const int idx = k * 256 + t;  // 0..1023 = 8 rows x 128 words
      const int r = idx >> 7, wd = idx & 127;
      const int* src = adj + (size_t)(rbase + r) * NN + wd * 32;
      unsigned int bits = 0;
#pragma unroll
      for (int s = 0; s < 8; ++s) {
        const int4 v = *(const int4*)&src[s * 4];
        bits |= (v.x ? 1u : 0u) << (s * 4 + 0);
        bits |= (v.y ? 1u : 0u) << (s * 4 + 1);
        bits |= (v.z ? 1u : 0u) << (s * 4 + 2);
        bits |= (v.w ? 1u : 0u) << (s * 4 + 3);
      }
      adjb[(size_t)(rbase + r) * NW32 + wd] = bits;
    }
  }

  // --- GEMM
  const int r0 = blockIdx.x * GROWS;
#pragma unroll
  for (int idx = t; idx < GROWS * FIN / 4; idx += 256) {
    const int r = idx >> 6, c4 = idx & 63;
    *(float4*)&hs[r][c4 * 4] =
        *(const float4*)&h[(size_t)(r0 + r) * FIN + c4 * 4];
  }
  __syncthreads();
  const int c = t;
  float acc[GROWS];
#pragma unroll
  for (int r = 0; r < GROWS; ++r) acc[r] = 0.f;
  for (int k = 0; k < FIN; k += 4) {
    const float w0 = W[(size_t)(k + 0) * CC + c];
    const float w1 = W[(size_t)(k + 1) * CC + c];
    const float w2 = W[(size_t)(k + 2) * CC + c];
    const float w3 = W[(size_t)(k + 3) * CC + c];
#pragma unroll
    for (int r = 0; r < GROWS; ++r) {
      const float4 hv = *(const float4*)&hs[r][k];
      acc[r] += hv.x * w0 + hv.y * w1 + hv.z * w2 + hv.w * w3;
    }
  }
  const int f = c & 31, hh = c >> 5;
  const float aS = a[f], aD = a[32 + f];
  unsigned short gu[GROWS];
#pragma unroll
  for (int r = 0; r < GROWS; ++r) {
    float ps = acc[r] * aS, pd = acc[r] * aD;
#pragma unroll
    for (int m = 1; m < 32; m <<= 1) {
      ps += __shfl_xor(ps, m, 64);
      pd += __shfl_xor(pd, m, 64);
    }
    if (f == 0) {
      const int n = r0 + r;
      spack[(size_t)hh * NN + n] =
          make_float4(ps, __expf(ps), __expf(0.2f * ps), 0.f);
      const size_t db = ((size_t)hh * (NN / 8) + (n >> 3)) * 24 + (n & 7);
      dtrip[db] = -pd;
      dtrip[db + 8] = __expf(pd);
      dtrip[db + 16] = __expf(0.2f * pd);
    }
    gu[r] = bf16rn(acc[r]);
  }
  uint4 gv;
  gv.x = (unsigned)gu[0] | ((unsigned)gu[1] << 16);
  gv.y = (unsigned)gu[2] | ((unsigned)gu[3] << 16);
  gv.z = (unsigned)gu[4] | ((unsigned)gu[5] << 16);
  gv.w = (unsigned)gu[6] | ((unsigned)gu[7] << 16);
  *(uint4*)(gT + (size_t)c * NN + r0) = gv;
}

// ---------------- K2: barrier-free, LDS-free fused softmax-weight + MFMA PV
// 256 thr = 4 independent waves; wave w -> heads {2w,2w+1}; 32-i block,
// j-split sp (XCD-pinned via bx&7). All operand streams L2-resident:
// adjb 2 b32, dtrip 6 float4/hp (one base, imm offsets), gT 2 short8/hp.
__global__ __launch_bounds__(256, 3) void k_attn(
    const unsigned int* __restrict__ adjb, const unsigned short* __restrict__ gT,
    const float4* __restrict__ spack, const float* __restrict__ dtrip,
    float* __restrict__ acc_ws, float* __restrict__ l_ws,
    float* __restrict__ out, const int splits, const int direct) {
  const int lane = threadIdx.x & 63;
  const int w = threadIdx.x >> 6;
  const int il = lane & 15, q = lane >> 4;
  const int bx = blockIdx.x;
  const int sp = bx & (splits - 1);
  const int ib = bx / splits;
  const int i0 = ib * 32;
  const int jrange = NN / splits, j0b = sp * jrange;
  const int hbase = w * 2;

  // hoisted i-side scalars
  float ssv[2][2], e1v[2][2], e2v[2][2];
#pragma unroll
  for (int hp = 0; hp < 2; ++hp)
#pragma unroll
    for (int it = 0; it < 2; ++it) {
      const float4 v = spack[(size_t)(hbase + hp) * NN + i0 + it * 16 + il];
      ssv[hp][it] = v.x; e1v[hp][it] = v.y; e2v[hp][it] = v.z;
    }

  f32x4 acc[2][2][2];
  f32x4 lac[2][2];
#pragma unroll
  for (int hp = 0; hp < 2; ++hp)
#pragma unroll
    for (int it = 0; it < 2; ++it) {
#pragma unroll
      for (int r = 0; r < 4; ++r) lac[hp][it][r] = 0.f;
#pragma unroll
      for (int ft = 0; ft < 2; ++ft)
#pragma unroll
        for (int r = 0; r < 4; ++r) acc[hp][it][ft][r] = 0.f;
    }

  const short8 ones = {(short)0x3F80, (short)0x3F80, (short)0x3F80,
                       (short)0x3F80, (short)0x3F80, (short)0x3F80,
                       (short)0x3F80, (short)0x3F80};

  // hoisted row pointers
  const unsigned int* ab0 = adjb + (size_t)(i0 + il) * NW32 + (j0b >> 5);
  const unsigned int* ab1 = adjb + (size_t)(i0 + 16 + il) * NW32 + (j0b >> 5);
  const unsigned short* gr[2][2];
  const float* dbase[2];
#pragma unroll
  for (int hp = 0; hp < 2; ++hp) {
    const int hh = hbase + hp;
    gr[hp][0] = gT + (size_t)(hh * 32 + il) * NN;
    gr[hp][1] = gT + (size_t)(hh * 32 + 16 + il) * NN;
    dbase[hp] =
        dtrip + ((size_t)hh * (NN / 8) + (j0b >> 3) + q) * 24;
  }
  const int sh = q * 8;

  const int nch = jrange / 32;
  for (int jc = 0; jc < nch; ++jc) {
    const int jq = j0b + jc * 32 + q * 8;
    const unsigned int bits0 = ab0[jc];
    const unsigned int bits1 = ab1[jc];
    float adf[2][8];
#pragma unroll
    for (int e = 0; e < 8; ++e) {
      adf[0][e] = (float)((bits0 >> (sh + e)) & 1u);
      adf[1][e] = (float)((bits1 >> (sh + e)) & 1u);
    }

#pragma unroll
    for (int hp = 0; hp < 2; ++hp) {
      const float* dp = dbase[hp] + (size_t)jc * 96;
      float nsd[8], e1j[8], e2j[8];
      *(float4*)&nsd[0] = *(const float4*)(dp + 0);
      *(float4*)&nsd[4] = *(const float4*)(dp + 4);
      *(float4*)&e1j[0] = *(const float4*)(dp + 8);
      *(float4*)&e1j[4] = *(const float4*)(dp + 12);
      *(float4*)&e2j[0] = *(const float4*)(dp + 16);
      *(float4*)&e2j[4] = *(const float4*)(dp + 20);
      const short8 b0 = *(const short8*)&gr[hp][0][jq];
      const short8 b1 = *(const short8*)&gr[hp][1][jq];
#pragma unroll
      for (int it = 0; it < 2; ++it) {
        const float ssl = ssv[hp][it];
        const float ei1 = e1v[hp][it], ei2 = e2v[hp][it];
        float wv[8];
#pragma unroll
        for (int e = 0; e < 8; ++e) {
          const bool pos = ssl > nsd[e];
          wv[e] = (pos ? ei1 : ei2) * (pos ? e1j[e] : e2j[e]) * adf[it][e];
        }
        u32x4 uu;
#pragma unroll
        for (int m = 0; m < 4; ++m)
          uu[m] = cvtpk_bf16(wv[2 * m], wv[2 * m + 1]);
        const short8 afr = __builtin_bit_cast(short8, uu);
        acc[hp][it][0] = __builtin_amdgcn_mfma_f32_16x16x32_bf16(
            afr, b0, acc[hp][it][0], 0, 0, 0);
        acc[hp][it][1] = __builtin_amdgcn_mfma_f32_16x16x32_bf16(
            afr, b1, acc[hp][it][1], 0, 0, 0);
        lac[hp][it] = __builtin_amdgcn_mfma_f32_16x16x32_bf16(
            afr, ones, lac[hp][it], 0, 0, 0);
      }
    }
  }

  if (direct) {
#pragma unroll
    for (int hp = 0; hp < 2; ++hp) {
      const int hh = hbase + hp;
#pragma unroll
      for (int it = 0; it < 2; ++it)
#pragma unroll
        for (int r = 0; r < 4; ++r) {
          const float inv = 1.f / lac[hp][it][r];
          const size_t irow = i0 + it * 16 + q * 4 + r;
#pragma unroll
          for (int ft = 0; ft < 2; ++ft)
            out[irow * CC + hh * 32 + ft * 16 + il] =
                acc[hp][it][ft][r] * inv;
        }
    }
  } else {
#pragma unroll
    for (int hp = 0; hp < 2; ++hp) {
      const int hh = hbase + hp;
#pragma unroll
      for (int it = 0; it < 2; ++it)
#pragma unroll
        for (int r = 0; r < 4; ++r) {
          const size_t irow = i0 + it * 16 + q * 4 + r;
          if (il == 0)
            l_ws[((size_t)sp * NH + hh) * NN + irow] = lac[hp][it][r];
#pragma unroll
          for (int ft = 0; ft < 2; ++ft)
            acc_ws[((size_t)sp * NN + irow) * CC + hh * 32 + ft * 16 + il] =
                acc[hp][it][ft][r];
        }
    }
  }
}

// ---------------- K3: combine split partials ----------------
__global__ __launch_bounds__(256) void k_combine(
    const float* __restrict__ acc_ws, const float* __restrict__ l_ws,
    float* __restrict__ out, const int splits) {
  const int idx = blockIdx.x * 256 + threadIdx.x;  // float4 index
  const int row = idx >> 6, c4 = idx & 63;
  const int hh = c4 >> 3;
  float ax = 0.f, ay = 0.f, az = 0.f, aw = 0.f, l = 0.f;
  for (int s = 0; s < splits; ++s) {
    const float4 v =
        *(const float4*)&acc_ws[((size_t)s * NN + row) * CC + c4 * 4];
    ax += v.x; ay += v.y; az += v.z; aw += v.w;
    l += l_ws[((size_t)s * NH + hh) * NN + row];
  }
  const float inv = 1.f / l;
  *(float4*)&out[(size_t)row * CC + c4 * 4] =
      make_float4(ax * inv, ay * inv, az * inv, aw * inv);
}

extern "C" void kernel_launch(void* const* d_in, const int* in_sizes, int n_in,
                              void* d_out, int out_size, void* d_ws,
                              size_t ws_size, hipStream_t stream) {
  (void)in_sizes; (void)n_in; (void)out_size;
  const float* h = (const float*)d_in[0];
  const int* adj = (const int*)d_in[1];
  const float* W = (const float*)d_in[2];
  const float* a = (const float*)d_in[3];
  float* out = (float*)d_out;
  char* ws = (char*)d_ws;

  unsigned short* gT = (unsigned short*)ws;               // 2 MB
  float4* spack = (float4*)(ws + (size_t)NN * CC * 2);    // 512 KB
  float* dtrip = (float*)(spack + (size_t)NH * NN);       // 384 KB (blocked)
  unsigned int* adjb =
      (unsigned int*)(dtrip + (size_t)NH * (NN / 8) * 24);  // 2 MB
  char* after = (char*)(adjb + (size_t)NN * NW32);
  const size_t base = (size_t)(after - ws);
  const size_t per_split = (size_t)NN * CC * 4 + (size_t)NH * NN * 4;

  int splits = 1;
  if (ws_size >= base + 8 * per_split) splits = 8;
  else if (ws_size >= base + 4 * per_split) splits = 4;
  else if (ws_size >= base + 2 * per_split) splits = 2;

  k_gemm<<<NN / GROWS, 256, 0, stream>>>(h, W, a, adj, adjb, gT, spack, dtrip);

  const int nblk = (NN / 32) * splits;
  if (splits == 1) {
    k_attn<<<nblk, 256, 0, stream>>>(adjb, gT, spack, dtrip, nullptr, nullptr,
                                     out, 1, 1);
  } else {
    float* acc_ws = (float*)after;
    float* l_ws = acc_ws + (size_t)splits * NN * CC;
    k_attn<<<nblk, 256, 0, stream>>>(adjb, gT, spack, dtrip, acc_ws, l_ws, out,
                                     splits, 0);
    k_combine<<<NN * CC / 4 / 256, 256, 0, stream>>>(acc_ws, l_ws, out,
                                                     splits);
  }
}

// Round 9
// 80.664 us; speedup vs baseline: 1.4889x; 1.4889x over previous
//
#include <hip/hip_runtime.h>

#define NN 4096
#define FIN 256
#define CC 256
#define NH 8
#define NW32 (NN / 32)  // u32 words per adj row

typedef __attribute__((ext_vector_type(8))) short short8;
typedef __attribute__((ext_vector_type(4))) float f32x4;
typedef __attribute__((ext_vector_type(4))) unsigned int u32x4;

__device__ __forceinline__ unsigned cvtpk_bf16(float lo, float hi) {
  unsigned r;
  asm("v_cvt_pk_bf16_f32 %0, %1, %2" : "=v"(r) : "v"(lo), "v"(hi));
  return r;
}

__device__ __forceinline__ unsigned short bf16rn(float x) {
  unsigned int u = __builtin_bit_cast(unsigned int, x);
  u += 0x7fffu + ((u >> 16) & 1u);
  return (unsigned short)(u >> 16);
}

__device__ __forceinline__ void gl_lds16(const void* g, void* l) {
  __builtin_amdgcn_global_load_lds(
      (const __attribute__((address_space(1))) void*)g,
      (__attribute__((address_space(3))) void*)l, 16, 0, 0);
}

// ---------------- K1: adj bitpack + g = h@W with fused epilogue ------------
// adjb[i][w] bit e = adj[i][w*32+e]!=0.
// gTs: chunk-major SWIZZLED bf16: unit(16B) at [jc][c][p], p = q ^ ((c>>1)&3)
//   holding g[j = jc*32 + q*8 .. +7][feature c]  (so linear global_load_lds
//   of a chunk produces the bank-swizzled LDS image directly).
// spack[h][n] = (s_src, e^s, e^.2s, 0).
// dtc[jc][3][NH][32] = (-s_dst, e^sd, e^{0.2 sd}) per chunk.
#define GROWS 8
__global__ __launch_bounds__(256) void k_gemm(
    const float* __restrict__ h, const float* __restrict__ W,
    const float* __restrict__ a, const int* __restrict__ adj,
    unsigned int* __restrict__ adjb, unsigned short* __restrict__ gTs,
    float4* __restrict__ spack, float* __restrict__ dtc) {
  __shared__ float hs[GROWS][FIN];
  const int t = threadIdx.x;

  // --- bitpack 8 adj rows (overlaps other blocks' GEMM; the 64MB HBM stream)
  {
    const int rbase = blockIdx.x * 8;
#pragma unroll
    for (int k = 0; k < 4; ++k) {
      const int idx = k * 256 + t;  // 8 rows x 128 words
      const int r = idx >> 7, wd = idx & 127;
      const int* src = adj + (size_t)(rbase + r) * NN + wd * 32;
      unsigned int bits = 0;
#pragma unroll
      for (int s = 0; s < 8; ++s) {
        const int4 v = *(const int4*)&src[s * 4];
        bits |= (v.x ? 1u : 0u) << (s * 4 + 0);
        bits |= (v.y ? 1u : 0u) << (s * 4 + 1);
        bits |= (v.z ? 1u : 0u) << (s * 4 + 2);
        bits |= (v.w ? 1u : 0u) << (s * 4 + 3);
      }
      adjb[(size_t)(rbase + r) * NW32 + wd] = bits;
    }
  }

  // --- GEMM
  const int r0 = blockIdx.x * GROWS;
#pragma unroll
  for (int idx = t; idx < GROWS * FIN / 4; idx += 256) {
    const int r = idx >> 6, c4 = idx & 63;
    *(float4*)&hs[r][c4 * 4] =
        *(const float4*)&h[(size_t)(r0 + r) * FIN + c4 * 4];
  }
  __syncthreads();
  const int c = t;
  float acc[GROWS];
#pragma unroll
  for (int r = 0; r < GROWS; ++r) acc[r] = 0.f;
  for (int k = 0; k < FIN; k += 4) {
    const float w0 = W[(size_t)(k + 0) * CC + c];
    const float w1 = W[(size_t)(k + 1) * CC + c];
    const float w2 = W[(size_t)(k + 2) * CC + c];
    const float w3 = W[(size_t)(k + 3) * CC + c];
#pragma unroll
    for (int r = 0; r < GROWS; ++r) {
      const float4 hv = *(const float4*)&hs[r][k];
      acc[r] += hv.x * w0 + hv.y * w1 + hv.z * w2 + hv.w * w3;
    }
  }
  const int f = c & 31, hh = c >> 5;
  const float aS = a[f], aD = a[32 + f];
  unsigned short gu[GROWS];
#pragma unroll
  for (int r = 0; r < GROWS; ++r) {
    float ps = acc[r] * aS, pd = acc[r] * aD;
#pragma unroll
    for (int m = 1; m < 32; m <<= 1) {
      ps += __shfl_xor(ps, m, 64);
      pd += __shfl_xor(pd, m, 64);
    }
    if (f == 0) {
      const int n = r0 + r;
      spack[(size_t)hh * NN + n] =
          make_float4(ps, __expf(ps), __expf(0.2f * ps), 0.f);
      float* dc = dtc + (size_t)(n >> 5) * 768 + hh * 32 + (n & 31);
      dc[0] = -pd;
      dc[256] = __expf(pd);
      dc[512] = __expf(0.2f * pd);
    }
    gu[r] = bf16rn(acc[r]);
  }
  uint4 gv;
  gv.x = (unsigned)gu[0] | ((unsigned)gu[1] << 16);
  gv.y = (unsigned)gu[2] | ((unsigned)gu[3] << 16);
  gv.z = (unsigned)gu[4] | ((unsigned)gu[5] << 16);
  gv.w = (unsigned)gu[6] | ((unsigned)gu[7] << 16);
  // swizzled unit store: this block's 8 nodes = unit q of chunk jc, row c
  const int jc = r0 >> 5, qq = (r0 >> 3) & 3;
  const int p = qq ^ ((c >> 1) & 3);
  *(uint4*)(gTs + ((size_t)jc * 1024 + c * 4 + p) * 8) = gv;
}

// ---------------- K2: LDS 2-phase fused masked-softmax + MFMA PV -----------
// Block = 64 i x 8 heads; 4 waves: wave w -> i-half (w>>1), head-quad (w&1).
// Staged gT chunk (16KB, swizzled) is read by ALL waves (4x reuse);
// dt 3KB broadcast-read; adj from bitpacked adjb (L2, 2 regs prefetch).
struct Buf {
  unsigned short gt[8192];  // 16 KB: unit u = c*4 + (q ^ ((c>>1)&3))
  float dt[3][NH][32];      // 3 KB
};

__global__ __launch_bounds__(256, 2) void k_attn(
    const unsigned int* __restrict__ adjb, const unsigned short* __restrict__ gTs,
    const float4* __restrict__ spack, const float* __restrict__ dtc,
    float* __restrict__ acc_ws, float* __restrict__ l_ws,
    float* __restrict__ out, const int splits, const int direct) {
  __shared__ Buf buf[2];  // 38 KB

  const int lane = threadIdx.x & 63;
  const int w = threadIdx.x >> 6;
  const int il = lane & 15, q = lane >> 4;
  const int bx = blockIdx.x;
  const int sp = bx & (splits - 1);
  const int ib = bx / splits;
  const int i0w = ib * 64 + (w >> 1) * 32;  // this wave's 32 i-rows
  const int hquad = w & 1;                  // heads hquad*4 .. +3
  const int jrange = NN / splits, j0b = sp * jrange;
  const int c0 = (j0b >> 5);                // first global chunk index

  // hoisted i-side scalars (4 heads x 2 it)
  float ssv[4][2], e1v[4][2], e2v[4][2];
#pragma unroll
  for (int hp = 0; hp < 4; ++hp)
#pragma unroll
    for (int it = 0; it < 2; ++it) {
      const float4 v =
          spack[(size_t)(hquad * 4 + hp) * NN + i0w + it * 16 + il];
      ssv[hp][it] = v.x; e1v[hp][it] = v.y; e2v[hp][it] = v.z;
    }

  f32x4 acc[4][2][2];
  f32x4 lac[4][2];
#pragma unroll
  for (int hp = 0; hp < 4; ++hp)
#pragma unroll
    for (int it = 0; it < 2; ++it) {
#pragma unroll
      for (int r = 0; r < 4; ++r) lac[hp][it][r] = 0.f;
#pragma unroll
      for (int ft = 0; ft < 2; ++ft)
#pragma unroll
        for (int r = 0; r < 4; ++r) acc[hp][it][ft][r] = 0.f;
    }

  const short8 ones = {(short)0x3F80, (short)0x3F80, (short)0x3F80,
                       (short)0x3F80, (short)0x3F80, (short)0x3F80,
                       (short)0x3F80, (short)0x3F80};

  const unsigned int* ab0 = adjb + (size_t)(i0w + il) * NW32 + (j0b >> 5);
  const unsigned int* ab1 = adjb + (size_t)(i0w + 16 + il) * NW32 + (j0b >> 5);
  const int sh = q * 8;
  const int sswz = (il >> 1) & 3;  // gt swizzle for this lane
  const int pswz = q ^ sswz;

  // ---- staging: linear 16KB gt + 3KB dt copy (pre-swizzled in global) ----
  auto stage = [&](Buf* b, int jc) {
    const unsigned short* src = gTs + (size_t)(c0 + jc) * 8192;
#pragma unroll
    for (int pass = 0; pass < 4; ++pass) {
      const int base = pass * 256 + w * 64;  // wave-uniform
      gl_lds16(src + (size_t)(base + lane) * 8, (char*)b->gt + base * 16);
    }
    if (w < 3) {
      const float* dsrc = dtc + (size_t)(c0 + jc) * 768;
      gl_lds16(dsrc + (size_t)(w * 64 + lane) * 4,
               (char*)&b->dt[0][0][0] + (w * 64) * 16);
    }
  };

  const int nch = jrange / 32;
  stage(&buf[0], 0);
  unsigned int pb0 = ab0[0], pb1 = ab1[0];
  __syncthreads();
  int cur = 0;

  for (int jc = 0; jc < nch; ++jc) {
    if (jc + 1 < nch) stage(&buf[cur ^ 1], jc + 1);
    const Buf* bc = &buf[cur];

    // adj bits -> float multipliers (shared across all 4 heads)
    float adf[2][8];
    {
      const unsigned int bits0 = pb0, bits1 = pb1;
#pragma unroll
      for (int e = 0; e < 8; ++e) {
        adf[0][e] = (float)((bits0 >> (sh + e)) & 1u);
        adf[1][e] = (float)((bits1 >> (sh + e)) & 1u);
      }
      if (jc + 1 < nch) { pb0 = ab0[jc + 1]; pb1 = ab1[jc + 1]; }
    }

#pragma unroll
    for (int hp = 0; hp < 4; ++hp) {
      const int hh = hquad * 4 + hp;
      float nsd[8], e1j[8], e2j[8];
      *(float4*)&nsd[0] = *(const float4*)&bc->dt[0][hh][q * 8];
      *(float4*)&nsd[4] = *(const float4*)&bc->dt[0][hh][q * 8 + 4];
      *(float4*)&e1j[0] = *(const float4*)&bc->dt[1][hh][q * 8];
      *(float4*)&e1j[4] = *(const float4*)&bc->dt[1][hh][q * 8 + 4];
      *(float4*)&e2j[0] = *(const float4*)&bc->dt[2][hh][q * 8];
      *(float4*)&e2j[4] = *(const float4*)&bc->dt[2][hh][q * 8 + 4];
      const int u0 = (hh * 32 + il) * 4 + pswz;        // swizzled unit
      const short8 b0 = *(const short8*)&bc->gt[u0 * 8];
      const short8 b1 = *(const short8*)&bc->gt[(u0 + 64) * 8];  // +16 rows
#pragma unroll
      for (int it = 0; it < 2; ++it) {
        const float ssl = ssv[hp][it];
        const float ei1 = e1v[hp][it], ei2 = e2v[hp][it];
        float wv[8];
#pragma unroll
        for (int e = 0; e < 8; ++e) {
          const bool pos = ssl > nsd[e];
          wv[e] = (pos ? ei1 : ei2) * (pos ? e1j[e] : e2j[e]) * adf[it][e];
        }
        u32x4 uu;
#pragma unroll
        for (int m = 0; m < 4; ++m)
          uu[m] = cvtpk_bf16(wv[2 * m], wv[2 * m + 1]);
        const short8 afr = __builtin_bit_cast(short8, uu);
        acc[hp][it][0] = __builtin_amdgcn_mfma_f32_16x16x32_bf16(
            afr, b0, acc[hp][it][0], 0, 0, 0);
        acc[hp][it][1] = __builtin_amdgcn_mfma_f32_16x16x32_bf16(
            afr, b1, acc[hp][it][1], 0, 0, 0);
        lac[hp][it] = __builtin_amdgcn_mfma_f32_16x16x32_bf16(
            afr, ones, lac[hp][it], 0, 0, 0);
      }
    }
    __syncthreads();  // drains staging vmcnt + read lgkm; swap safe
    cur ^= 1;
  }

  if (direct) {
#pragma unroll
    for (int hp = 0; hp < 4; ++hp) {
      const int hh = hquad * 4 + hp;
#pragma unroll
      for (int it = 0; it < 2; ++it)
#pragma unroll
        for (int r = 0; r < 4; ++r) {
          const float inv = 1.f / lac[hp][it][r];
          const size_t irow = i0w + it * 16 + q * 4 + r;
#pragma unroll
          for (int ft = 0; ft < 2; ++ft)
            out[irow * CC + hh * 32 + ft * 16 + il] =
                acc[hp][it][ft][r] * inv;
        }
    }
  } else {
#pragma unroll
    for (int hp = 0; hp < 4; ++hp) {
      const int hh = hquad * 4 + hp;
#pragma unroll
      for (int it = 0; it < 2; ++it)
#pragma unroll
        for (int r = 0; r < 4; ++r) {
          const size_t irow = i0w + it * 16 + q * 4 + r;
          if (il == 0)
            l_ws[((size_t)sp * NH + hh) * NN + irow] = lac[hp][it][r];
#pragma unroll
          for (int ft = 0; ft < 2; ++ft)
            acc_ws[((size_t)sp * NN + irow) * CC + hh * 32 + ft * 16 + il] =
                acc[hp][it][ft][r];
        }
    }
  }
}

// ---------------- K3: combine split partials ----------------
__global__ __launch_bounds__(256) void k_combine(
    const float* __restrict__ acc_ws, const float* __restrict__ l_ws,
    float* __restrict__ out, const int splits) {
  const int idx = blockIdx.x * 256 + threadIdx.x;  // float4 index
  const int row = idx >> 6, c4 = idx & 63;
  const int hh = c4 >> 3;
  float ax = 0.f, ay = 0.f, az = 0.f, aw = 0.f, l = 0.f;
  for (int s = 0; s < splits; ++s) {
    const float4 v =
        *(const float4*)&acc_ws[((size_t)s * NN + row) * CC + c4 * 4];
    ax += v.x; ay += v.y; az += v.z; aw += v.w;
    l += l_ws[((size_t)s * NH + hh) * NN + row];
  }
  const float inv = 1.f / l;
  *(float4*)&out[(size_t)row * CC + c4 * 4] =
      make_float4(ax * inv, ay * inv, az * inv, aw * inv);
}

extern "C" void kernel_launch(void* const* d_in, const int* in_sizes, int n_in,
                              void* d_out, int out_size, void* d_ws,
                              size_t ws_size, hipStream_t stream) {
  (void)in_sizes; (void)n_in; (void)out_size;
  const float* h = (const float*)d_in[0];
  const int* adj = (const int*)d_in[1];
  const float* W = (const float*)d_in[2];
  const float* a = (const float*)d_in[3];
  float* out = (float*)d_out;
  char* ws = (char*)d_ws;

  unsigned short* gTs = (unsigned short*)ws;               // 2 MB (swizzled)
  float4* spack = (float4*)(ws + (size_t)NN * CC * 2);     // 512 KB
  float* dtc = (float*)(spack + (size_t)NH * NN);          // 384 KB (chunked)
  unsigned int* adjb =
      (unsigned int*)(dtc + (size_t)(NN / 32) * 768);      // 2 MB
  char* after = (char*)(adjb + (size_t)NN * NW32);
  const size_t base = (size_t)(after - ws);
  const size_t per_split = (size_t)NN * CC * 4 + (size_t)NH * NN * 4;

  int splits = 1;
  if (ws_size >= base + 8 * per_split) splits = 8;
  else if (ws_size >= base + 4 * per_split) splits = 4;
  else if (ws_size >= base + 2 * per_split) splits = 2;

  k_gemm<<<NN / GROWS, 256, 0, stream>>>(h, W, a, adj, adjb, gTs, spack, dtc);

  const int nblk = (NN / 64) * splits;
  if (splits == 1) {
    k_attn<<<nblk, 256, 0, stream>>>(adjb, gTs, spack, dtc, nullptr, nullptr,
                                     out, 1, 1);
  } else {
    float* acc_ws = (float*)after;
    float* l_ws = acc_ws + (size_t)splits * NN * CC;
    k_attn<<<nblk, 256, 0, stream>>>(adjb, gTs, spack, dtc, acc_ws, l_ws, out,
                                     splits, 0);
    k_combine<<<NN * CC / 4 / 256, 256, 0, stream>>>(acc_ws, l_ws, out,
                                                     splits);
  }
}